// Round 3
// baseline (165.752 us; speedup 1.0000x reference)
//
#include <hip/hip_runtime.h>

#define B_     128
#define S_     256
#define MW_    21
#define VOCAB_ 100
#define EC_    50
#define EW_    256
#define KW_    5
#define T_     17              // MW - K + 1
#define NW_    (B_ * S_)       // 32768 words
#define GROWS  (VOCAB_ * KW_)  // 500
#define WPB    128             // words per conv block

typedef __bf16 bf16x8 __attribute__((ext_vector_type(8)));
typedef float  f32x4  __attribute__((ext_vector_type(4)));

__device__ __forceinline__ float bf2f(unsigned short u) {
  union { unsigned int i; float f; } x; x.i = ((unsigned int)u) << 16; return x.f;
}
__device__ __forceinline__ unsigned short f2bf(float f) {
  union { float f; unsigned int i; } x; x.f = f;
  unsigned int r = x.i + 0x7fffu + ((x.i >> 16) & 1u);  // RNE
  return (unsigned short)(r >> 16);
}

// ---------------- kernel 1: g[v*5+k][o] = sum_i emb[v][i] * conv_w[o][i][k]
// emb, cw are float32; g stored bf16 (feeds LDS slice + keeps it 64 KB)
__global__ __launch_bounds__(256) void k_g(const float* __restrict__ emb,
                                           const float* __restrict__ cw,
                                           unsigned short* __restrict__ g) {
  __shared__ float es[EC_];
  const int v = blockIdx.x / KW_;
  const int k = blockIdx.x % KW_;
  const int o = threadIdx.x;
  if (threadIdx.x < EC_) es[threadIdx.x] = emb[v * EC_ + threadIdx.x];
  __syncthreads();
  float acc = 0.f;
#pragma unroll
  for (int i = 0; i < EC_; ++i)
    acc += es[i] * cw[(o * EC_ + i) * KW_ + k];
  g[blockIdx.x * EW_ + o] = f2bf(acc);
}

// ---------------- kernel 2: conv + relu + maxpool via g-gather
// y[n][o] = max_t relu(cb[o] + sum_k g[idx[n][t+k]][k][o]);  y stored bf16
// LDS: 500 rows x 64ch x 2B = 64000 B  (< 64 KB workgroup limit)
__global__ __launch_bounds__(256) void k_conv(const int* __restrict__ idx,
                                              const unsigned short* __restrict__ g,
                                              const float* __restrict__ cb,
                                              unsigned short* __restrict__ y) {
  __shared__ __align__(16) unsigned short g_s[GROWS * 64];
  const int tid   = threadIdx.x;
  const int chunk = blockIdx.x & 3;    // which 64-channel slice
  const int wg    = blockIdx.x >> 2;   // word group
  const int oc0   = chunk * 64;
  const int wbase = wg * WPB;

  for (int c = tid; c < GROWS * 8; c += 256) {
    const int row = c >> 3, cc = c & 7;
    *(uint4*)&g_s[row * 64 + cc * 8] =
        *(const uint4*)&g[row * EW_ + oc0 + cc * 8];
  }
  __syncthreads();

  const int wave = tid >> 6, lane = tid & 63;
  const int wq = lane >> 3, og = lane & 7;  // 8 words x 8 channel-octets per wave

  float bias[8];
#pragma unroll
  for (int j = 0; j < 8; ++j) bias[j] = cb[oc0 + og * 8 + j];

  for (int oct = wave; oct < WPB / 8; oct += 4) {
    const int wl = oct * 8 + wq;
    const int* __restrict__ ip = idx + (wbase + wl) * MW_;
    int boff[MW_];
#pragma unroll
    for (int c = 0; c < MW_; ++c)
      boff[c] = ip[c] * (KW_ * 64) + og * 8;

    float mx[8];
#pragma unroll
    for (int j = 0; j < 8; ++j) mx[j] = 0.f;  // relu => max >= 0

#pragma unroll
    for (int t = 0; t < T_; ++t) {
      float s[8];
#pragma unroll
      for (int j = 0; j < 8; ++j) s[j] = bias[j];
#pragma unroll
      for (int k = 0; k < KW_; ++k) {
        const bf16x8 gv = *(const bf16x8*)&g_s[boff[t + k] + k * 64];
#pragma unroll
        for (int j = 0; j < 8; ++j) s[j] += (float)gv[j];
      }
#pragma unroll
      for (int j = 0; j < 8; ++j) mx[j] = fmaxf(mx[j], s[j]);
    }

    const unsigned int w0 = (unsigned int)f2bf(mx[0]) | ((unsigned int)f2bf(mx[1]) << 16);
    const unsigned int w1 = (unsigned int)f2bf(mx[2]) | ((unsigned int)f2bf(mx[3]) << 16);
    const unsigned int w2 = (unsigned int)f2bf(mx[4]) | ((unsigned int)f2bf(mx[5]) << 16);
    const unsigned int w3 = (unsigned int)f2bf(mx[6]) | ((unsigned int)f2bf(mx[7]) << 16);
    *(uint4*)&y[(wbase + wl) * EW_ + oc0 + og * 8] = make_uint4(w0, w1, w2, w3);
  }
}

// ---------------- kernel 3: highway, fused dual MFMA GEMM
// proj = relu(Y @ Wp^T + bp); gate = sigmoid(Y @ Wg^T + bg); out = gate*proj + (1-gate)*Y
// Y is bf16 (ws); Wp/Wg/bp/bg are float32 (converted to bf16 while staging); out float32
__global__ __launch_bounds__(256) void k_highway(const unsigned short* __restrict__ Y,
                                                 const float* __restrict__ Wp,
                                                 const float* __restrict__ Wg,
                                                 const float* __restrict__ bp,
                                                 const float* __restrict__ bg,
                                                 float* __restrict__ out) {
  __shared__ __align__(16) unsigned short As[128][32];
  __shared__ __align__(16) unsigned short Bps[64][32];
  __shared__ __align__(16) unsigned short Bgs[64][32];
  const int tid  = threadIdx.x;
  const int wave = tid >> 6, lane = tid & 63;
  const int wm = wave >> 1, wn = wave & 1;
  const int quad = lane >> 4, r16 = lane & 15;
  const int m0 = blockIdx.x * 128;
  const int n0 = blockIdx.y * 64;

  f32x4 accp[4][2], accg[4][2];
  const f32x4 zero = {0.f, 0.f, 0.f, 0.f};
#pragma unroll
  for (int i = 0; i < 4; ++i)
#pragma unroll
    for (int j = 0; j < 2; ++j) { accp[i][j] = zero; accg[i][j] = zero; }

  for (int k0 = 0; k0 < EW_; k0 += 32) {
    // A tile: 128 rows x 32 cols bf16 from Y
#pragma unroll
    for (int c = 0; c < 2; ++c) {
      const int ch = c * 256 + tid;        // 512 chunks of 16B
      const int r = ch >> 2, cc = ch & 3;
      *(uint4*)&As[r][cc * 8] = *(const uint4*)&Y[(m0 + r) * EW_ + k0 + cc * 8];
    }
    // B tiles: 64 rows x 32 cols, f32 -> bf16 convert on the fly
    {
      const int r = tid >> 2, cc = tid & 3;
      const float* wp8 = &Wp[(n0 + r) * EW_ + k0 + cc * 8];
      const float* wg8 = &Wg[(n0 + r) * EW_ + k0 + cc * 8];
      unsigned short tp[8], tg[8];
#pragma unroll
      for (int j = 0; j < 8; ++j) { tp[j] = f2bf(wp8[j]); tg[j] = f2bf(wg8[j]); }
#pragma unroll
      for (int j = 0; j < 8; ++j) { Bps[r][cc * 8 + j] = tp[j]; Bgs[r][cc * 8 + j] = tg[j]; }
    }
    __syncthreads();

    bf16x8 a[4], bpv[2], bgv[2];
#pragma unroll
    for (int mi = 0; mi < 4; ++mi)
      a[mi] = *(const bf16x8*)&As[wm * 64 + mi * 16 + r16][quad * 8];
#pragma unroll
    for (int ni = 0; ni < 2; ++ni) {
      bpv[ni] = *(const bf16x8*)&Bps[wn * 32 + ni * 16 + r16][quad * 8];
      bgv[ni] = *(const bf16x8*)&Bgs[wn * 32 + ni * 16 + r16][quad * 8];
    }
#pragma unroll
    for (int mi = 0; mi < 4; ++mi)
#pragma unroll
      for (int ni = 0; ni < 2; ++ni) {
        accp[mi][ni] = __builtin_amdgcn_mfma_f32_16x16x32_bf16(a[mi], bpv[ni], accp[mi][ni], 0, 0, 0);
        accg[mi][ni] = __builtin_amdgcn_mfma_f32_16x16x32_bf16(a[mi], bgv[ni], accg[mi][ni], 0, 0, 0);
      }
    __syncthreads();
  }

#pragma unroll
  for (int mi = 0; mi < 4; ++mi)
#pragma unroll
    for (int ni = 0; ni < 2; ++ni) {
      const int n = n0 + wn * 32 + ni * 16 + r16;
      const float bpn = bp[n];
      const float bgn = bg[n];
#pragma unroll
      for (int reg = 0; reg < 4; ++reg) {
        const int m = m0 + wm * 64 + mi * 16 + quad * 4 + reg;
        float p = accp[mi][ni][reg] + bpn;
        p = fmaxf(p, 0.f);
        const float gz = accg[mi][ni][reg] + bgn;
        const float gate = 1.f / (1.f + __expf(-gz));
        const float yv = bf2f(Y[m * EW_ + n]);
        out[m * EW_ + n] = gate * p + (1.f - gate) * yv;
      }
    }
}

extern "C" void kernel_launch(void* const* d_in, const int* in_sizes, int n_in,
                              void* d_out, int out_size, void* d_ws, size_t ws_size,
                              hipStream_t stream) {
  (void)in_sizes; (void)n_in; (void)out_size; (void)ws_size;
  const int*   idx = (const int*)d_in[0];
  const float* emb = (const float*)d_in[1];
  const float* cw  = (const float*)d_in[2];
  const float* cb  = (const float*)d_in[3];
  const float* wp  = (const float*)d_in[4];
  const float* bpp = (const float*)d_in[5];
  const float* wgt = (const float*)d_in[6];
  const float* bgg = (const float*)d_in[7];
  float* out = (float*)d_out;
  unsigned short* g_ws = (unsigned short*)d_ws;          // 500*256 bf16 = 256000 B
  unsigned short* y_ws = g_ws + GROWS * EW_;             // 32768*256 bf16 = 16 MB

  k_g<<<GROWS, 256, 0, stream>>>(emb, cw, g_ws);
  k_conv<<<(NW_ / WPB) * 4, 256, 0, stream>>>(idx, g_ws, cb, y_ws);
  k_highway<<<dim3(NW_ / 128, EW_ / 64), 256, 0, stream>>>(y_ws, wp, wgt, bpp, bgg, out);
}

// Round 4
// 164.897 us; speedup vs baseline: 1.0052x; 1.0052x over previous
//
#include <hip/hip_runtime.h>

#define B_     128
#define S_     256
#define MW_    21
#define VOCAB_ 100
#define EC_    50
#define EW_    256
#define KW_    5
#define T_     17              // MW - K + 1
#define NW_    (B_ * S_)       // 32768 words
#define GROWS  (VOCAB_ * KW_)  // 500
#define WPB    128             // words per conv block

typedef __bf16 bf16x8 __attribute__((ext_vector_type(8)));
typedef float  f32x4  __attribute__((ext_vector_type(4)));
typedef float  f32x2  __attribute__((ext_vector_type(2)));

__device__ __forceinline__ float bf2f(unsigned short u) {
  union { unsigned int i; float f; } x; x.i = ((unsigned int)u) << 16; return x.f;
}
__device__ __forceinline__ unsigned short f2bf(float f) {
  union { float f; unsigned int i; } x; x.f = f;
  unsigned int r = x.i + 0x7fffu + ((x.i >> 16) & 1u);  // RNE
  return (unsigned short)(r >> 16);
}
__device__ __forceinline__ float asf(unsigned int u) {
  union { unsigned int i; float f; } x; x.i = u; return x.f;
}

// ---------------- kernel 1: g[v*5+k][o] = sum_i emb[v][i] * conv_w[o][i][k]
__global__ __launch_bounds__(256) void k_g(const float* __restrict__ emb,
                                           const float* __restrict__ cw,
                                           unsigned short* __restrict__ g) {
  __shared__ float es[EC_];
  const int v = blockIdx.x / KW_;
  const int k = blockIdx.x % KW_;
  const int o = threadIdx.x;
  if (threadIdx.x < EC_) es[threadIdx.x] = emb[v * EC_ + threadIdx.x];
  __syncthreads();
  float acc = 0.f;
#pragma unroll
  for (int i = 0; i < EC_; ++i)
    acc += es[i] * cw[(o * EC_ + i) * KW_ + k];
  g[blockIdx.x * EW_ + o] = f2bf(acc);
}

// ---------------- kernel 1b: weights f32 -> bf16 (once)
__global__ __launch_bounds__(256) void k_wcvt(const float* __restrict__ Wp,
                                              const float* __restrict__ Wg,
                                              unsigned short* __restrict__ wpb,
                                              unsigned short* __restrict__ wgb) {
  const int i = (blockIdx.x * 256 + threadIdx.x) * 8;  // 8 elems per thread
  const float4 p0 = *(const float4*)&Wp[i], p1 = *(const float4*)&Wp[i + 4];
  const float4 g0 = *(const float4*)&Wg[i], g1 = *(const float4*)&Wg[i + 4];
  uint4 up, ug;
  up.x = f2bf(p0.x) | ((unsigned)f2bf(p0.y) << 16);
  up.y = f2bf(p0.z) | ((unsigned)f2bf(p0.w) << 16);
  up.z = f2bf(p1.x) | ((unsigned)f2bf(p1.y) << 16);
  up.w = f2bf(p1.z) | ((unsigned)f2bf(p1.w) << 16);
  ug.x = f2bf(g0.x) | ((unsigned)f2bf(g0.y) << 16);
  ug.y = f2bf(g0.z) | ((unsigned)f2bf(g0.w) << 16);
  ug.z = f2bf(g1.x) | ((unsigned)f2bf(g1.y) << 16);
  ug.w = f2bf(g1.z) | ((unsigned)f2bf(g1.w) << 16);
  *(uint4*)&wpb[i] = up;
  *(uint4*)&wgb[i] = ug;
}

// ---------------- kernel 2: conv + relu + maxpool via g-gather
// y[n][o] = max_t relu(cb[o] + sum_k g[idx[n][t+k]][k][o]);  y stored bf16
// LDS: 500 rows x 64ch x 2B = 64000 B; 512 thr -> 16 waves/CU resident
__global__ __launch_bounds__(512, 4) void k_conv(const int* __restrict__ idx,
                                                 const unsigned short* __restrict__ g,
                                                 const float* __restrict__ cb,
                                                 unsigned short* __restrict__ y) {
  __shared__ __align__(16) unsigned short g_s[GROWS * 64];
  const int tid   = threadIdx.x;
  const int chunk = blockIdx.x & 3;    // which 64-channel slice
  const int wg    = blockIdx.x >> 2;   // word group
  const int oc0   = chunk * 64;
  const int wbase = wg * WPB;

  for (int c = tid; c < GROWS * 8; c += 512) {
    const int row = c >> 3, cc = c & 7;
    *(uint4*)&g_s[row * 64 + cc * 8] =
        *(const uint4*)&g[row * EW_ + oc0 + cc * 8];
  }
  __syncthreads();

  const int wave = tid >> 6, lane = tid & 63;
  const int wq = lane >> 3, og = lane & 7;  // 8 words x 8 channel-octets per wave

  f32x2 bias2[4];
#pragma unroll
  for (int j = 0; j < 4; ++j) {
    bias2[j][0] = cb[oc0 + og * 8 + 2 * j];
    bias2[j][1] = cb[oc0 + og * 8 + 2 * j + 1];
  }

  for (int oct = wave; oct < WPB / 8; oct += 8) {
    const int wl = oct * 8 + wq;
    const int* __restrict__ ip = idx + (wbase + wl) * MW_;
    int boff[MW_];
#pragma unroll
    for (int c = 0; c < MW_; ++c)
      boff[c] = ip[c] * (KW_ * 64) + og * 8;

    f32x2 mx[4];
#pragma unroll
    for (int j = 0; j < 4; ++j) mx[j] = (f32x2){0.f, 0.f};  // relu => max >= 0

#pragma unroll
    for (int t = 0; t < T_; ++t) {
      f32x2 s[4];
#pragma unroll
      for (int j = 0; j < 4; ++j) s[j] = bias2[j];
#pragma unroll
      for (int k = 0; k < KW_; ++k) {
        const uint4 gv = *(const uint4*)&g_s[boff[t + k] + k * 64];
        const unsigned int d[4] = {gv.x, gv.y, gv.z, gv.w};
#pragma unroll
        for (int j = 0; j < 4; ++j) {
          f32x2 v;
          v[0] = asf(d[j] << 16);
          v[1] = asf(d[j] & 0xffff0000u);
          s[j] += v;                      // v_pk_add_f32
        }
      }
#pragma unroll
      for (int j = 0; j < 4; ++j) mx[j] = __builtin_elementwise_max(mx[j], s[j]);
    }

    uint4 w;
    w.x = (unsigned)f2bf(mx[0][0]) | ((unsigned)f2bf(mx[0][1]) << 16);
    w.y = (unsigned)f2bf(mx[1][0]) | ((unsigned)f2bf(mx[1][1]) << 16);
    w.z = (unsigned)f2bf(mx[2][0]) | ((unsigned)f2bf(mx[2][1]) << 16);
    w.w = (unsigned)f2bf(mx[3][0]) | ((unsigned)f2bf(mx[3][1]) << 16);
    *(uint4*)&y[(wbase + wl) * EW_ + oc0 + og * 8] = w;
  }
}

// ---------------- kernel 3: highway, fused dual MFMA GEMM
// proj = relu(Y @ Wp^T + bp); gate = sigmoid(Y @ Wg^T + bg); out = gate*proj + (1-gate)*Y
// Y, wpb, wgb bf16; bp/bg f32; out f32
__global__ __launch_bounds__(256) void k_highway(const unsigned short* __restrict__ Y,
                                                 const unsigned short* __restrict__ wpb,
                                                 const unsigned short* __restrict__ wgb,
                                                 const float* __restrict__ bp,
                                                 const float* __restrict__ bg,
                                                 float* __restrict__ out) {
  __shared__ __align__(16) unsigned short As[128][32];
  __shared__ __align__(16) unsigned short Bps[64][32];
  __shared__ __align__(16) unsigned short Bgs[64][32];
  const int tid  = threadIdx.x;
  const int wave = tid >> 6, lane = tid & 63;
  const int wm = wave >> 1, wn = wave & 1;
  const int quad = lane >> 4, r16 = lane & 15;
  const int m0 = blockIdx.x * 128;
  const int n0 = blockIdx.y * 64;

  f32x4 accp[4][2], accg[4][2];
  const f32x4 zero = {0.f, 0.f, 0.f, 0.f};
#pragma unroll
  for (int i = 0; i < 4; ++i)
#pragma unroll
    for (int j = 0; j < 2; ++j) { accp[i][j] = zero; accg[i][j] = zero; }

  for (int k0 = 0; k0 < EW_; k0 += 32) {
    // A tile: 128 rows x 32 cols bf16 from Y
#pragma unroll
    for (int c = 0; c < 2; ++c) {
      const int ch = c * 256 + tid;        // 512 chunks of 16B
      const int r = ch >> 2, cc = ch & 3;
      *(uint4*)&As[r][cc * 8] = *(const uint4*)&Y[(m0 + r) * EW_ + k0 + cc * 8];
    }
    // B tiles: 64 rows x 32 cols bf16
    {
      const int r = tid >> 2, cc = tid & 3;
      *(uint4*)&Bps[r][cc * 8] = *(const uint4*)&wpb[(n0 + r) * EW_ + k0 + cc * 8];
      *(uint4*)&Bgs[r][cc * 8] = *(const uint4*)&wgb[(n0 + r) * EW_ + k0 + cc * 8];
    }
    __syncthreads();

    bf16x8 a[4], bpv[2], bgv[2];
#pragma unroll
    for (int mi = 0; mi < 4; ++mi)
      a[mi] = *(const bf16x8*)&As[wm * 64 + mi * 16 + r16][quad * 8];
#pragma unroll
    for (int ni = 0; ni < 2; ++ni) {
      bpv[ni] = *(const bf16x8*)&Bps[wn * 32 + ni * 16 + r16][quad * 8];
      bgv[ni] = *(const bf16x8*)&Bgs[wn * 32 + ni * 16 + r16][quad * 8];
    }
#pragma unroll
    for (int mi = 0; mi < 4; ++mi)
#pragma unroll
      for (int ni = 0; ni < 2; ++ni) {
        accp[mi][ni] = __builtin_amdgcn_mfma_f32_16x16x32_bf16(a[mi], bpv[ni], accp[mi][ni], 0, 0, 0);
        accg[mi][ni] = __builtin_amdgcn_mfma_f32_16x16x32_bf16(a[mi], bgv[ni], accg[mi][ni], 0, 0, 0);
      }
    __syncthreads();
  }

#pragma unroll
  for (int mi = 0; mi < 4; ++mi)
#pragma unroll
    for (int ni = 0; ni < 2; ++ni) {
      const int n = n0 + wn * 32 + ni * 16 + r16;
      const float bpn = bp[n];
      const float bgn = bg[n];
#pragma unroll
      for (int reg = 0; reg < 4; ++reg) {
        const int m = m0 + wm * 64 + mi * 16 + quad * 4 + reg;
        float p = accp[mi][ni][reg] + bpn;
        p = fmaxf(p, 0.f);
        const float gz = accg[mi][ni][reg] + bgn;
        const float gate = 1.f / (1.f + __expf(-gz));
        const float yv = bf2f(Y[m * EW_ + n]);
        out[m * EW_ + n] = gate * p + (1.f - gate) * yv;
      }
    }
}

extern "C" void kernel_launch(void* const* d_in, const int* in_sizes, int n_in,
                              void* d_out, int out_size, void* d_ws, size_t ws_size,
                              hipStream_t stream) {
  (void)in_sizes; (void)n_in; (void)out_size; (void)ws_size;
  const int*   idx = (const int*)d_in[0];
  const float* emb = (const float*)d_in[1];
  const float* cw  = (const float*)d_in[2];
  const float* cb  = (const float*)d_in[3];
  const float* wp  = (const float*)d_in[4];
  const float* bpp = (const float*)d_in[5];
  const float* wgt = (const float*)d_in[6];
  const float* bgg = (const float*)d_in[7];
  float* out = (float*)d_out;
  unsigned short* g_ws = (unsigned short*)d_ws;          // 500*256 bf16
  unsigned short* y_ws = g_ws + GROWS * EW_;             // 32768*256 bf16
  unsigned short* wp_b = y_ws + NW_ * EW_;               // 256*256 bf16
  unsigned short* wg_b = wp_b + EW_ * EW_;               // 256*256 bf16

  k_g<<<GROWS, 256, 0, stream>>>(emb, cw, g_ws);
  k_wcvt<<<EW_ * EW_ / (256 * 8), 256, 0, stream>>>(wp, wgt, wp_b, wg_b);
  k_conv<<<(NW_ / WPB) * 4, 512, 0, stream>>>(idx, g_ws, cb, y_ws);
  k_highway<<<dim3(NW_ / 128, EW_ / 64), 256, 0, stream>>>(y_ws, wp_b, wg_b, bpp, bgg, out);
}

// Round 5
// 131.952 us; speedup vs baseline: 1.2562x; 1.2497x over previous
//
#include <hip/hip_runtime.h>

#define B_     128
#define S_     256
#define MW_    21
#define VOCAB_ 100
#define EC_    50
#define EW_    256
#define KW_    5
#define T_     17              // MW - K + 1
#define NW_    (B_ * S_)       // 32768 words
#define GROWS  (VOCAB_ * KW_)  // 500
#define WPB    128             // words per mega block
#define GS_STRIDE 72           // g_s row stride (halves): 64 ch + 8 pad  -> 144B rows
#define YS_STRIDE 264          // y_s row stride (halves): 256 ch + 8 pad -> 528B rows
#define BS_STRIDE 40           // B_s row stride (halves): 32 k + 8 pad   -> 80B rows

typedef _Float16 f16x8 __attribute__((ext_vector_type(8)));
typedef float    f32x4 __attribute__((ext_vector_type(4)));

// ---------------- kernel 1: prep
// blocks [0,500): g[v*5+k][o] = sum_i emb[v][i]*conv_w[o][i][k]  (fp16)
// blocks [500,532): convert Wp/Wg f32 -> fp16
__global__ __launch_bounds__(256) void k_prep(const float* __restrict__ emb,
                                              const float* __restrict__ cw,
                                              const float* __restrict__ Wp,
                                              const float* __restrict__ Wg,
                                              _Float16* __restrict__ g,
                                              _Float16* __restrict__ wph,
                                              _Float16* __restrict__ wgh) {
  const int bi = blockIdx.x;
  if (bi < GROWS) {
    __shared__ float es[EC_];
    const int v = bi / KW_;
    const int k = bi % KW_;
    const int o = threadIdx.x;
    if (threadIdx.x < EC_) es[threadIdx.x] = emb[v * EC_ + threadIdx.x];
    __syncthreads();
    float acc = 0.f;
#pragma unroll
    for (int i = 0; i < EC_; ++i)
      acc += es[i] * cw[(o * EC_ + i) * KW_ + k];
    g[bi * EW_ + o] = (_Float16)acc;
  } else {
    const int i = ((bi - GROWS) * 256 + threadIdx.x) * 8;  // covers 256*256
    const float4 p0 = *(const float4*)&Wp[i], p1 = *(const float4*)&Wp[i + 4];
    const float4 q0 = *(const float4*)&Wg[i], q1 = *(const float4*)&Wg[i + 4];
    f16x8 hp = {(_Float16)p0.x, (_Float16)p0.y, (_Float16)p0.z, (_Float16)p0.w,
                (_Float16)p1.x, (_Float16)p1.y, (_Float16)p1.z, (_Float16)p1.w};
    f16x8 hg = {(_Float16)q0.x, (_Float16)q0.y, (_Float16)q0.z, (_Float16)q0.w,
                (_Float16)q1.x, (_Float16)q1.y, (_Float16)q1.z, (_Float16)q1.w};
    *(f16x8*)&wph[i] = hp;
    *(f16x8*)&wgh[i] = hg;
  }
}

// ---------------- kernel 2: mega — conv+relu+maxpool (phase A) + dual GEMM highway (phase B)
// One block per 128 words; y tile lives only in LDS.
__global__ __launch_bounds__(512, 2) void k_mega(const int* __restrict__ idx,
                                                 const _Float16* __restrict__ g,
                                                 const float* __restrict__ cb,
                                                 const _Float16* __restrict__ wph,
                                                 const _Float16* __restrict__ wgh,
                                                 const float* __restrict__ bp,
                                                 const float* __restrict__ bg,
                                                 float* __restrict__ out) {
  __shared__ __align__(16) _Float16 g_s[GROWS * GS_STRIDE];  // 72000 B (reused for B tiles)
  __shared__ __align__(16) _Float16 y_s[WPB * YS_STRIDE];    // 67584 B
  const int tid  = threadIdx.x;
  const int wave = tid >> 6, lane = tid & 63;
  const int m0 = blockIdx.x * WPB;

  // ======== phase A: conv + relu + maxpool -> y_s[word][ch] fp16 ========
  const int wq = lane >> 3, og = lane & 7;   // 8 words x 8 channel-octets per wave
#pragma unroll
  for (int chunk = 0; chunk < 4; ++chunk) {
    const int oc0 = chunk * 64;
    // stage g slice: 500 rows x 64 ch, padded stride
    for (int c = tid; c < GROWS * 8; c += 512) {
      const int row = c >> 3, cc = c & 7;
      *(f16x8*)&g_s[row * GS_STRIDE + cc * 8] =
          *(const f16x8*)&g[row * EW_ + oc0 + cc * 8];
    }
    __syncthreads();

    f16x8 bias;
#pragma unroll
    for (int j = 0; j < 8; ++j) bias[j] = (_Float16)cb[oc0 + og * 8 + j];

#pragma unroll
    for (int it = 0; it < 2; ++it) {
      const int wl = it * 64 + wave * 8 + wq;
      const int* __restrict__ ip = idx + (m0 + wl) * MW_;
      int base[MW_];
#pragma unroll
      for (int c = 0; c < MW_; ++c)
        base[c] = ip[c] * (KW_ * GS_STRIDE) + og * 8;

      f16x8 mx = {0, 0, 0, 0, 0, 0, 0, 0};  // relu => max >= 0
#pragma unroll
      for (int t = 0; t < T_; ++t) {
        f16x8 s = bias;
#pragma unroll
        for (int k = 0; k < KW_; ++k)
          s += *(const f16x8*)&g_s[base[t + k] + k * GS_STRIDE];  // v_pk_add_f16
        mx = __builtin_elementwise_max(mx, s);                     // v_pk_max_f16
      }
      *(f16x8*)&y_s[wl * YS_STRIDE + oc0 + og * 8] = mx;
    }
    __syncthreads();  // protect g_s before restage / reuse
  }

  // ======== phase B: dual GEMM (proj & gate) + highway epilogue ========
  _Float16* Bp_s = g_s;                       // 256 x BS_STRIDE
  _Float16* Bg_s = g_s + EW_ * BS_STRIDE;     // 256 x BS_STRIDE (total 40960 B < 72000)
  const int wm = wave >> 1;                   // 4 m-tiles of 32 rows
  const int wn = wave & 1;                    // 2 n-tiles of 128 cols
  const int quad = lane >> 4, r16 = lane & 15;

  f32x4 accp[2][8], accg[2][8];
  const f32x4 zero = {0.f, 0.f, 0.f, 0.f};
#pragma unroll
  for (int mi = 0; mi < 2; ++mi)
#pragma unroll
    for (int nf = 0; nf < 8; ++nf) { accp[mi][nf] = zero; accg[mi][nf] = zero; }

  for (int k0 = 0; k0 < EW_; k0 += 32) {
    // stage B k-slices (both weight matrices), 256 rows x 32 k
#pragma unroll
    for (int i2 = 0; i2 < 2; ++i2) {
      const int c2 = i2 * 512 + tid;
      const int r = c2 >> 2, cc = c2 & 3;
      *(f16x8*)&Bp_s[r * BS_STRIDE + cc * 8] = *(const f16x8*)&wph[r * EW_ + k0 + cc * 8];
      *(f16x8*)&Bg_s[r * BS_STRIDE + cc * 8] = *(const f16x8*)&wgh[r * EW_ + k0 + cc * 8];
    }
    __syncthreads();

    f16x8 a[2];
#pragma unroll
    for (int mi = 0; mi < 2; ++mi)
      a[mi] = *(const f16x8*)&y_s[(wm * 32 + mi * 16 + r16) * YS_STRIDE + k0 + quad * 8];

#pragma unroll
    for (int nf = 0; nf < 8; ++nf) {
      const int n = wn * 128 + nf * 16 + r16;
      const f16x8 bpv = *(const f16x8*)&Bp_s[n * BS_STRIDE + quad * 8];
      const f16x8 bgv = *(const f16x8*)&Bg_s[n * BS_STRIDE + quad * 8];
#pragma unroll
      for (int mi = 0; mi < 2; ++mi) {
        accp[mi][nf] = __builtin_amdgcn_mfma_f32_16x16x32_f16(a[mi], bpv, accp[mi][nf], 0, 0, 0);
        accg[mi][nf] = __builtin_amdgcn_mfma_f32_16x16x32_f16(a[mi], bgv, accg[mi][nf], 0, 0, 0);
      }
    }
    __syncthreads();  // before restaging B next k-step
  }

  // epilogue: bias + relu + sigmoid + highway blend, f32 out
#pragma unroll
  for (int mi = 0; mi < 2; ++mi)
#pragma unroll
    for (int nf = 0; nf < 8; ++nf) {
      const int n = wn * 128 + nf * 16 + r16;
      const float bpn = bp[n];
      const float bgn = bg[n];
#pragma unroll
      for (int reg = 0; reg < 4; ++reg) {
        const int m = wm * 32 + mi * 16 + quad * 4 + reg;
        float p = fmaxf(accp[mi][nf][reg] + bpn, 0.f);
        const float gz = accg[mi][nf][reg] + bgn;
        const float gate = 1.f / (1.f + __expf(-gz));
        const float yv = (float)y_s[m * YS_STRIDE + n];
        out[(m0 + m) * EW_ + n] = gate * p + (1.f - gate) * yv;
      }
    }
}

extern "C" void kernel_launch(void* const* d_in, const int* in_sizes, int n_in,
                              void* d_out, int out_size, void* d_ws, size_t ws_size,
                              hipStream_t stream) {
  (void)in_sizes; (void)n_in; (void)out_size; (void)ws_size;
  const int*   idx = (const int*)d_in[0];
  const float* emb = (const float*)d_in[1];
  const float* cw  = (const float*)d_in[2];
  const float* cb  = (const float*)d_in[3];
  const float* wp  = (const float*)d_in[4];
  const float* bpp = (const float*)d_in[5];
  const float* wgt = (const float*)d_in[6];
  const float* bgg = (const float*)d_in[7];
  float* out = (float*)d_out;
  _Float16* g_ws = (_Float16*)d_ws;            // 500*256 fp16 = 256000 B
  _Float16* wp_h = g_ws + GROWS * EW_;         // 256*256 fp16 = 131072 B
  _Float16* wg_h = wp_h + EW_ * EW_;           // 256*256 fp16

  k_prep<<<GROWS + 32, 256, 0, stream>>>(emb, cw, wp, wgt, g_ws, wp_h, wg_h);
  k_mega<<<NW_ / WPB, 512, 0, stream>>>(idx, g_ws, cb, wp_h, wg_h, bpp, bgg, out);
}

// Round 6
// 131.359 us; speedup vs baseline: 1.2618x; 1.0045x over previous
//
#include <hip/hip_runtime.h>

#define B_     128
#define S_     256
#define MW_    21
#define VOCAB_ 100
#define EC_    50
#define EW_    256
#define KW_    5
#define T_     17              // MW - K + 1
#define NW_    (B_ * S_)       // 32768 words
#define GROWS  (VOCAB_ * KW_)  // 500
#define WPB    128             // words per mega block

typedef _Float16 f16x8 __attribute__((ext_vector_type(8)));
typedef float    f32x4 __attribute__((ext_vector_type(4)));

// ---------------- kernel 1: prep
// blocks [0,500): g[v*5+k][o] = sum_i emb[v][i]*conv_w[o][i][k]  (fp16, row-major [row][256])
// blocks [500,532): Wp/Wg f32 -> fp16 in MFMA B-fragment order:
//   frag f = nt*8+ks (nt 0..15, ks 0..7), lane l holds W[nt*16+(l&15)][ks*32+(l>>4)*8 + j]
__global__ __launch_bounds__(256) void k_prep(const float* __restrict__ emb,
                                              const float* __restrict__ cw,
                                              const float* __restrict__ Wp,
                                              const float* __restrict__ Wg,
                                              _Float16* __restrict__ g,
                                              _Float16* __restrict__ wpf,
                                              _Float16* __restrict__ wgf) {
  const int bi = blockIdx.x;
  if (bi < GROWS) {
    __shared__ float es[EC_];
    const int v = bi / KW_;
    const int k = bi % KW_;
    const int o = threadIdx.x;
    if (threadIdx.x < EC_) es[threadIdx.x] = emb[v * EC_ + threadIdx.x];
    __syncthreads();
    float acc = 0.f;
#pragma unroll
    for (int i = 0; i < EC_; ++i)
      acc += es[i] * cw[(o * EC_ + i) * KW_ + k];
    g[bi * EW_ + o] = (_Float16)acc;
  } else {
    const int fl  = (bi - GROWS) * 256 + threadIdx.x;  // 0..8191 lane-frags
    const int nt  = fl >> 9;
    const int rem = fl & 511;
    const int ks  = rem >> 6;
    const int l   = rem & 63;
    const int n   = nt * 16 + (l & 15);
    const int kc  = ks * 32 + (l >> 4) * 8;
    const int src = n * EW_ + kc;
    const float4 p0 = *(const float4*)&Wp[src], p1 = *(const float4*)&Wp[src + 4];
    const float4 q0 = *(const float4*)&Wg[src], q1 = *(const float4*)&Wg[src + 4];
    f16x8 hp = {(_Float16)p0.x, (_Float16)p0.y, (_Float16)p0.z, (_Float16)p0.w,
                (_Float16)p1.x, (_Float16)p1.y, (_Float16)p1.z, (_Float16)p1.w};
    f16x8 hg = {(_Float16)q0.x, (_Float16)q0.y, (_Float16)q0.z, (_Float16)q0.w,
                (_Float16)q1.x, (_Float16)q1.y, (_Float16)q1.z, (_Float16)q1.w};
    *(f16x8*)&wpf[fl * 8] = hp;
    *(f16x8*)&wgf[fl * 8] = hg;
  }
}

// ---------------- kernel 2: mega — conv+relu+maxpool (A) + dual-GEMM highway (B)
// LDS: y_s 65536 B (A-fragment layout) + g_s/B_s union 65536 B = 131072 B, 1 block/CU
__global__ __launch_bounds__(512, 2) void k_mega(const int* __restrict__ idx,
                                                 const _Float16* __restrict__ g,
                                                 const float* __restrict__ cb,
                                                 const _Float16* __restrict__ wpf,
                                                 const _Float16* __restrict__ wgf,
                                                 const float* __restrict__ bp,
                                                 const float* __restrict__ bg,
                                                 float* __restrict__ out) {
  __shared__ __align__(16) _Float16 lds[65536];
  _Float16* y_s = lds;            // 32768 halves: frag(mt,ks)*512 + lane*8 + j
  _Float16* g_s = lds + 32768;    // phase A: [500][64]
  _Float16* B_s = lds + 32768;    // phase B: 64 frags * 512 halves (one matrix half)

  const int tid  = threadIdx.x;
  const int wave = tid >> 6, lane = tid & 63;
  const int m0 = blockIdx.x * WPB;

  // ======== phase A: conv + relu + maxpool -> y_s fragments ========
  const int wq = lane >> 3, og = lane & 7;   // 8 words x 8 channel-octets per wave
#pragma unroll
  for (int chunk = 0; chunk < 4; ++chunk) {
    const int oc0 = chunk * 64;
    for (int c = tid; c < GROWS * 8; c += 512) {
      const int row = c >> 3, cc = c & 7;
      *(f16x8*)&g_s[row * 64 + cc * 8] = *(const f16x8*)&g[row * EW_ + oc0 + cc * 8];
    }
    __syncthreads();

    f16x8 bias;
#pragma unroll
    for (int j = 0; j < 8; ++j) bias[j] = (_Float16)cb[oc0 + og * 8 + j];

    const int ks_w   = chunk * 2 + (og >> 2);        // frag k-slice this octet lands in
    const int lane_hi = (og & 3) << 4;               // quad part of target lane

#pragma unroll
    for (int it = 0; it < 2; ++it) {
      const int wl = it * 64 + wave * 8 + wq;
      const int* __restrict__ ip = idx + (m0 + wl) * MW_;
      int base[MW_];
#pragma unroll
      for (int c = 0; c < MW_; ++c)
        base[c] = ip[c] * (KW_ * 64) + og * 8;

      f16x8 mx = {0, 0, 0, 0, 0, 0, 0, 0};  // relu => max >= 0
#pragma unroll
      for (int t = 0; t < T_; ++t) {
        f16x8 s = bias;
#pragma unroll
        for (int k = 0; k < KW_; ++k)
          s += *(const f16x8*)&g_s[base[t + k] + k * 64];   // v_pk_add_f16
        mx = __builtin_elementwise_max(mx, s);               // v_pk_max_f16
      }
      const int mt = wl >> 4;
      const int lane_t = (wl & 15) | lane_hi;
      *(f16x8*)&y_s[((mt * 8 + ks_w) * 64 + lane_t) * 8] = mx;
    }
    __syncthreads();  // y_s complete for this chunk; g_s safe to restage
  }

  // ======== phase B: dual GEMM + highway ========
  // waves: mtp = wave>>1 owns m-tiles {2mtp, 2mtp+1}; nh = wave&1 owns 64-col half of stage
  const int mtp = wave >> 1, nh = wave & 1;
  const int quad = lane >> 4, r16 = lane & 15;

  f16x8 a[2][8];
#pragma unroll
  for (int mi = 0; mi < 2; ++mi)
#pragma unroll
    for (int ks = 0; ks < 8; ++ks)
      a[mi][ks] = *(const f16x8*)&y_s[(((mtp * 2 + mi) * 8 + ks) * 64 + lane) * 8];

  const f32x4 zero = {0.f, 0.f, 0.f, 0.f};
#pragma unroll
  for (int h = 0; h < 2; ++h) {   // n-half: cols h*128 .. h*128+127
    f32x4 accp[2][4], accg[2][4];
#pragma unroll
    for (int mi = 0; mi < 2; ++mi)
#pragma unroll
      for (int nf = 0; nf < 4; ++nf) { accp[mi][nf] = zero; accg[mi][nf] = zero; }

#pragma unroll
    for (int mat = 0; mat < 2; ++mat) {
      const _Float16* __restrict__ src = (mat == 0 ? wpf : wgf) + h * 32768;
      // stage 64 frags (128 n-cols, full K) — coalesced, conflict-free
      for (int c = tid; c < 4096; c += 512)
        *(f16x8*)&B_s[c * 8] = *(const f16x8*)&src[c * 8];
      __syncthreads();

#pragma unroll
      for (int nf = 0; nf < 4; ++nf) {
        const int ntl = nh * 4 + nf;
#pragma unroll
        for (int ks = 0; ks < 8; ++ks) {
          const f16x8 bv = *(const f16x8*)&B_s[((ntl * 8 + ks) * 64 + lane) * 8];
          if (mat == 0) {
#pragma unroll
            for (int mi = 0; mi < 2; ++mi)
              accp[mi][nf] = __builtin_amdgcn_mfma_f32_16x16x32_f16(a[mi][ks], bv, accp[mi][nf], 0, 0, 0);
          } else {
#pragma unroll
            for (int mi = 0; mi < 2; ++mi)
              accg[mi][nf] = __builtin_amdgcn_mfma_f32_16x16x32_f16(a[mi][ks], bv, accg[mi][nf], 0, 0, 0);
          }
        }
      }
      __syncthreads();  // all waves done with B_s before restage
    }

    // epilogue for this n-half
#pragma unroll
    for (int mi = 0; mi < 2; ++mi) {
      const int mt = mtp * 2 + mi;
#pragma unroll
      for (int nf = 0; nf < 4; ++nf) {
        const int n = h * 128 + nh * 64 + nf * 16 + r16;
        const float bpn = bp[n];
        const float bgn = bg[n];
        const int ks_e = n >> 5;
        const int lane_e = ((n >> 3) & 3) << 4;
        const int je = n & 7;
#pragma unroll
        for (int reg = 0; reg < 4; ++reg) {
          const int m = mt * 16 + quad * 4 + reg;
          float p = fmaxf(accp[mi][nf][reg] + bpn, 0.f);
          const float gz = accg[mi][nf][reg] + bgn;
          const float gate = 1.f / (1.f + __expf(-gz));
          const float yv = (float)y_s[((mt * 8 + ks_e) * 64 + ((m & 15) | lane_e)) * 8 + je];
          out[(m0 + m) * EW_ + n] = gate * p + (1.f - gate) * yv;
        }
      }
    }
  }
}

extern "C" void kernel_launch(void* const* d_in, const int* in_sizes, int n_in,
                              void* d_out, int out_size, void* d_ws, size_t ws_size,
                              hipStream_t stream) {
  (void)in_sizes; (void)n_in; (void)out_size; (void)ws_size;
  const int*   idx = (const int*)d_in[0];
  const float* emb = (const float*)d_in[1];
  const float* cw  = (const float*)d_in[2];
  const float* cb  = (const float*)d_in[3];
  const float* wp  = (const float*)d_in[4];
  const float* bpp = (const float*)d_in[5];
  const float* wgt = (const float*)d_in[6];
  const float* bgg = (const float*)d_in[7];
  float* out = (float*)d_out;
  _Float16* g_ws = (_Float16*)d_ws;            // 500*256 fp16
  _Float16* wp_f = g_ws + GROWS * EW_;         // 65536 halves, frag order
  _Float16* wg_f = wp_f + EW_ * EW_;           // 65536 halves, frag order

  k_prep<<<GROWS + 32, 256, 0, stream>>>(emb, cw, wp, wgt, g_ws, wp_f, wg_f);
  k_mega<<<NW_ / WPB, 512, 0, stream>>>(idx, g_ws, cb, wp_f, wg_f, bpp, bgg, out);
}